// Round 1
// baseline (99.838 us; speedup 1.0000x reference)
//
#include <hip/hip_runtime.h>

// GaussianRenderer: N=512 gaussians -> 256x256x3 f32 image.
// Kernel 1 (1 block): per-gaussian transform + conic + stable depth-rank,
//   writes sorted 12-float records to d_ws.
// Kernel 2 (256 blocks x 256 thr): per-pixel front-to-back accumulation,
//   T = cumprod(1-alpha) INCLUDING current term (matches jnp.cumprod), w = alpha*T.

constexpr int   NGMAX = 1024;   // LDS depth array bound (N=512 here)
constexpr int   REC   = 12;     // floats per sorted gaussian record (48B)
constexpr int   WIMG  = 256;
constexpr int   HIMG  = 256;
constexpr float LOG2E = 1.4426950408889634f;
constexpr float INV2PI = 0.15915494309189535f;

__global__ __launch_bounds__(NGMAX) void gs_preprocess(
    const float* __restrict__ means3D, const float* __restrict__ covs3d,
    const float* __restrict__ colors,  const float* __restrict__ opac,
    const float* __restrict__ Km,      const float* __restrict__ Rm,
    const float* __restrict__ tvec,    float* __restrict__ recs, int N)
{
    __shared__ float s_depth[NGMAX];
    const int i = threadIdx.x;

    float Kl[9], Rl[9], tl[3];
    #pragma unroll
    for (int k = 0; k < 9; ++k) { Kl[k] = Km[k]; Rl[k] = Rm[k]; }
    tl[0] = tvec[0]; tl[1] = tvec[1]; tl[2] = tvec[2];

    float depth = 3.0e38f;
    float rec[REC];
    if (i < N) {
        const float m0 = means3D[i*3+0], m1 = means3D[i*3+1], m2 = means3D[i*3+2];
        float cam0 = Rl[0]*m0 + Rl[1]*m1 + Rl[2]*m2 + tl[0];
        float cam1 = Rl[3]*m0 + Rl[4]*m1 + Rl[5]*m2 + tl[1];
        float cam2 = Rl[6]*m0 + Rl[7]*m1 + Rl[8]*m2 + tl[2];
        const float Z = cam2;
        depth = fmaxf(Z, 1.0f);

        // screen = K @ cam ; means2D = screen.xy / screen.z
        const float s0 = Kl[0]*cam0 + Kl[1]*cam1 + Kl[2]*cam2;
        const float s1 = Kl[3]*cam0 + Kl[4]*cam1 + Kl[5]*cam2;
        const float s2 = Kl[6]*cam0 + Kl[7]*cam1 + Kl[8]*cam2;
        const float mx = s0 / s2, my = s1 / s2;

        const float fx = Kl[0], fy = Kl[4];
        const float iz = 1.0f / Z;
        float J[2][3];
        J[0][0] = fx*iz; J[0][1] = 0.0f;  J[0][2] = -fx*cam0*iz*iz;
        J[1][0] = 0.0f;  J[1][1] = fy*iz; J[1][2] = -fy*cam1*iz*iz;

        float S[9];
        #pragma unroll
        for (int k = 0; k < 9; ++k) S[k] = covs3d[i*9+k];

        // RS = R*S ; Ccam = RS*R^T
        float RS[9], Cc[9];
        #pragma unroll
        for (int r = 0; r < 3; ++r)
            #pragma unroll
            for (int c = 0; c < 3; ++c)
                RS[r*3+c] = Rl[r*3+0]*S[0+c] + Rl[r*3+1]*S[3+c] + Rl[r*3+2]*S[6+c];
        #pragma unroll
        for (int r = 0; r < 3; ++r)
            #pragma unroll
            for (int c = 0; c < 3; ++c)
                Cc[r*3+c] = RS[r*3+0]*Rl[c*3+0] + RS[r*3+1]*Rl[c*3+1] + RS[r*3+2]*Rl[c*3+2];

        // JC = J*Ccam (2x3) ; c2 = JC*J^T (2x2) + 1e-4 I
        float JC[2][3];
        #pragma unroll
        for (int r = 0; r < 2; ++r)
            #pragma unroll
            for (int c = 0; c < 3; ++c)
                JC[r][c] = J[r][0]*Cc[0+c] + J[r][1]*Cc[3+c] + J[r][2]*Cc[6+c];

        const float c200 = JC[0][0]*J[0][0] + JC[0][1]*J[0][1] + JC[0][2]*J[0][2] + 1e-4f;
        const float c201 = JC[0][0]*J[1][0] + JC[0][1]*J[1][1] + JC[0][2]*J[1][2];
        const float c210 = JC[1][0]*J[0][0] + JC[1][1]*J[0][1] + JC[1][2]*J[0][2];
        const float c211 = JC[1][0]*J[1][0] + JC[1][1]*J[1][1] + JC[1][2]*J[1][2] + 1e-4f;

        const float det  = c200*c211 - c201*c210;
        const float idet = 1.0f / det;
        // inv = [[c211,-c201],[-c210,c200]]/det ; expo = -0.5*(ia dx^2 + (i01+i10) dxdy + ic dy^2)
        const float ia  = c211*idet;
        const float ibs = -(c201 + c210)*idet;   // inv01+inv10
        const float ic  = c200*idet;

        const bool valid = (depth > 1.0f) && (depth < 50.0f);
        const float nrm  = valid ? (INV2PI / sqrtf(det)) : 0.0f;

        rec[0] = mx;
        rec[1] = my;
        rec[2] = -0.5f*LOG2E*ia;    // A
        rec[3] = -0.5f*LOG2E*ibs;   // B (covers both off-diagonals)
        rec[4] = -0.5f*LOG2E*ic;    // C
        rec[5] = opac[i] * nrm;     // opn (valid & norm folded in)
        rec[6] = colors[i*3+0];
        rec[7] = colors[i*3+1];
        rec[8] = colors[i*3+2];
        rec[9] = 0.0f; rec[10] = 0.0f; rec[11] = 0.0f;
    }

    s_depth[i] = depth;
    __syncthreads();

    if (i < N) {
        // stable argsort rank
        int rank = 0;
        for (int j = 0; j < N; ++j) {
            const float dj = s_depth[j];
            rank += (dj < depth) || (dj == depth && j < i);
        }
        float4* dst = (float4*)(recs + rank*REC);
        dst[0] = make_float4(rec[0], rec[1], rec[2],  rec[3]);
        dst[1] = make_float4(rec[4], rec[5], rec[6],  rec[7]);
        dst[2] = make_float4(rec[8], rec[9], rec[10], rec[11]);
    }
}

__global__ __launch_bounds__(256) void gs_render(
    const float* __restrict__ recs, float* __restrict__ out, int N)
{
    const float px = (float)threadIdx.x;
    const float py = (float)blockIdx.x;

    float T = 1.0f, cr = 0.0f, cg = 0.0f, cb = 0.0f;

    #pragma unroll 4
    for (int n = 0; n < N; ++n) {
        const float4* g4 = (const float4*)(recs + n*REC);
        const float4 p0 = g4[0];   // mx, my, A, B
        const float4 p1 = g4[1];   // C, opn, cr, cg
        const float  b8 = recs[n*REC + 8];  // cb

        const float dx = px - p0.x;
        const float dy = py - p0.y;
        const float e2 = fmaf(p0.z, dx*dx, fmaf(p0.w, dx*dy, p1.x*dy*dy));
        const float gau = __builtin_amdgcn_exp2f(e2);
        const float al  = p1.y * gau;
        T *= (1.0f - al);          // cumprod INCLUDES current term
        const float w = al * T;
        cr = fmaf(w, p1.z, cr);
        cg = fmaf(w, p1.w, cg);
        cb = fmaf(w, b8,  cb);
    }

    const int o = ((int)blockIdx.x * WIMG + (int)threadIdx.x) * 3;
    out[o+0] = cr;
    out[o+1] = cg;
    out[o+2] = cb;
}

extern "C" void kernel_launch(void* const* d_in, const int* in_sizes, int n_in,
                              void* d_out, int out_size, void* d_ws, size_t ws_size,
                              hipStream_t stream)
{
    const float* means3D = (const float*)d_in[0];
    const float* covs3d  = (const float*)d_in[1];
    const float* colors  = (const float*)d_in[2];
    const float* opac    = (const float*)d_in[3];
    const float* Km      = (const float*)d_in[4];
    const float* Rm      = (const float*)d_in[5];
    const float* tv      = (const float*)d_in[6];
    const int N = in_sizes[3];               // opacities: (N,)

    float* recs = (float*)d_ws;              // N*REC floats = 24 KB
    float* out  = (float*)d_out;

    gs_preprocess<<<1, NGMAX, 0, stream>>>(means3D, covs3d, colors, opac,
                                           Km, Rm, tv, recs, N);
    gs_render<<<dim3(HIMG), dim3(WIMG), 0, stream>>>(recs, out, N);
}